// Round 2
// baseline (276.034 us; speedup 1.0000x reference)
//
#include <hip/hip_runtime.h>
#include <hip/hip_bf16.h>

#define N_NODES 4096
#define DIMC    256   // H*D, also K of both layer GEMMs
#define NHEADS  4

typedef __attribute__((ext_vector_type(8))) short  short8;
typedef __attribute__((ext_vector_type(4))) short  short4v;
typedef __attribute__((ext_vector_type(4))) float  float4v;

union S8U { short8 v; unsigned int u[4]; };

__device__ inline unsigned short bf16_bits(__hip_bfloat16 b) {
  union { __hip_bfloat16 b; unsigned short u; } cv; cv.b = b; return cv.u;
}

// ---------------- adjacency -> bitmask (1 bit per edge) ----------------
__global__ __launch_bounds__(256) void pack_adj_kernel(
    const int* __restrict__ adj, unsigned long long* __restrict__ bits)
{
  int wid  = blockIdx.x * 4 + (threadIdx.x >> 6);
  int lane = threadIdx.x & 63;
  int row  = wid >> 6;
  int w64  = wid & 63;
  int v = adj[(size_t)row * N_NODES + w64 * 64 + lane];
  unsigned long long m = __ballot(v > 0);
  if (lane == 0) bits[row * 64 + w64] = m;
}

// ------------- fp32 -> split bf16 (hi + residual lo), elementwise --------
__global__ __launch_bounds__(256) void split_kernel(
    const float* __restrict__ in, __hip_bfloat16* __restrict__ hi,
    __hip_bfloat16* __restrict__ lo, int n)
{
  int i = blockIdx.x * 256 + threadIdx.x;
  if (i < n) {
    float v = in[i];
    __hip_bfloat16 h = __float2bfloat16(v);
    hi[i] = h;
    lo[i] = __float2bfloat16(v - __bfloat162float(h));
  }
}

// ------- fp32 transpose + split: in[B][R][C] -> outhi/lo[B][C][R] --------
// grid (R/32, C/32, B), block 256
__global__ __launch_bounds__(256) void transpose_split_kernel(
    const float* __restrict__ in, __hip_bfloat16* __restrict__ outhi,
    __hip_bfloat16* __restrict__ outlo, int R, int C)
{
  __shared__ float tile[32][33];
  int t = threadIdx.x;
  int r0 = blockIdx.x * 32, c0 = blockIdx.y * 32;
  size_t base = (size_t)blockIdx.z * R * C;
  int tr = t >> 3, tc = (t & 7) * 4;
  const float* ip = in + base;
  float4v v = *reinterpret_cast<const float4v*>(ip + (size_t)(r0 + tr) * C + c0 + tc);
#pragma unroll
  for (int k = 0; k < 4; ++k) tile[tr][tc + k] = v[k];
  __syncthreads();
  short4v oh, ol;
#pragma unroll
  for (int k = 0; k < 4; ++k) {
    float f = tile[tc + k][tr];
    __hip_bfloat16 hb = __float2bfloat16(f);
    __hip_bfloat16 lb = __float2bfloat16(f - __bfloat162float(hb));
    oh[k] = (short)bf16_bits(hb);
    ol[k] = (short)bf16_bits(lb);
  }
  size_t oidx = base + (size_t)(c0 + tr) * R + r0 + tc;
  *reinterpret_cast<short4v*>(reinterpret_cast<unsigned short*>(outhi) + oidx) = oh;
  *reinterpret_cast<short4v*>(reinterpret_cast<unsigned short*>(outlo) + oidx) = ol;
}

// ---------------- h GEMM (split-bf16): out[n][c] = sum_k X[n][k]*WT[c][k] --
// M=4096, N=256, K=256. grid (64,4), block 256 (4 waves x 16 rows, 64 cols)
__global__ __launch_bounds__(256) void gemm_kernel(
    const __hip_bfloat16* __restrict__ Xhi, const __hip_bfloat16* __restrict__ Xlo,
    const __hip_bfloat16* __restrict__ WThi, const __hip_bfloat16* __restrict__ WTlo,
    float* __restrict__ out)
{
  int t = threadIdx.x;
  int wv = t >> 6, lane = t & 63, quad = lane >> 4, col = lane & 15;
  int r0 = blockIdx.x * 64 + wv * 16;
  int c0 = blockIdx.y * 64;
  float4v acc[4] = {{0,0,0,0},{0,0,0,0},{0,0,0,0},{0,0,0,0}};
  const unsigned short* Xh = reinterpret_cast<const unsigned short*>(Xhi);
  const unsigned short* Xl = reinterpret_cast<const unsigned short*>(Xlo);
  const unsigned short* Wh = reinterpret_cast<const unsigned short*>(WThi);
  const unsigned short* Wl = reinterpret_cast<const unsigned short*>(WTlo);
#pragma unroll
  for (int k0 = 0; k0 < DIMC; k0 += 32) {
    size_t aoff = (size_t)(r0 + col) * DIMC + k0 + quad * 8;
    short8 ah = *reinterpret_cast<const short8*>(Xh + aoff);
    short8 al = *reinterpret_cast<const short8*>(Xl + aoff);
#pragma unroll
    for (int db = 0; db < 4; ++db) {
      size_t boff = (size_t)(c0 + db * 16 + col) * DIMC + k0 + quad * 8;
      short8 bh = *reinterpret_cast<const short8*>(Wh + boff);
      short8 bl = *reinterpret_cast<const short8*>(Wl + boff);
      acc[db] = __builtin_amdgcn_mfma_f32_16x16x32_bf16(ah, bh, acc[db], 0, 0, 0);
      acc[db] = __builtin_amdgcn_mfma_f32_16x16x32_bf16(ah, bl, acc[db], 0, 0, 0);
      acc[db] = __builtin_amdgcn_mfma_f32_16x16x32_bf16(al, bh, acc[db], 0, 0, 0);
    }
  }
#pragma unroll
  for (int db = 0; db < 4; ++db)
#pragma unroll
    for (int r = 0; r < 4; ++r)
      out[(size_t)(r0 + quad * 4 + r) * DIMC + c0 + db * 16 + col] = acc[db][r];
}

// ---------------- f1/f2 vectors from split hT ----------------------------
// grid (16, 4): block handles 256 consecutive n for head h
__global__ __launch_bounds__(256) void fvec_kernel(
    const __hip_bfloat16* __restrict__ hThi, const __hip_bfloat16* __restrict__ hTlo,
    const float* __restrict__ a, float* __restrict__ f1, float* __restrict__ f2)
{
  int h = blockIdx.y;
  int n = blockIdx.x * 256 + threadIdx.x;
  float s1 = 0.f, s2 = 0.f;
#pragma unroll 8
  for (int d = 0; d < 64; ++d) {
    size_t idx = (size_t)(h * 64 + d) * N_NODES + n;
    float hv = __bfloat162float(hThi[idx]) + __bfloat162float(hTlo[idx]);
    s1 += hv * a[h * 128 + d];
    s2 += hv * a[h * 128 + 64 + d];
  }
  f1[h * N_NODES + n] = s1;
  f2[h * N_NODES + n] = s2;
}

// ---------------- per-head max of f2 -------------------------------------
__global__ __launch_bounds__(256) void fmax_kernel(
    const float* __restrict__ f2, float* __restrict__ f2max)
{
  __shared__ float red[256];
  int h = blockIdx.x, t = threadIdx.x;
  float m = -1e30f;
  for (int n = t; n < N_NODES; n += 256) m = fmaxf(m, f2[h * N_NODES + n]);
  red[t] = m;
  __syncthreads();
  for (int s = 128; s > 0; s >>= 1) {
    if (t < s) red[t] = fmaxf(red[t], red[t + s]);
    __syncthreads();
  }
  if (t == 0) f2max[h] = red[0];
}

// ---------------- fused masked-softmax-numerator @ h  --------------------
// grid (NC, 64, 4): (j-chunk, row-tile of 64, head). block 256 = 4 waves x 16 rows.
__global__ __launch_bounds__(256) void attn_kernel(
    const __hip_bfloat16* __restrict__ hThi,  // [256][4096], row c = h*64+d
    const __hip_bfloat16* __restrict__ hTlo,
    const float* __restrict__ f1, const float* __restrict__ f2,
    const float* __restrict__ f2max,
    const unsigned int* __restrict__ bits32,  // [4096][128]
    float* __restrict__ pbuf, float* __restrict__ lbuf, int Jc)
{
  __shared__ __align__(16) unsigned short hsH[64 * 40]; // stride 40 u16 = 80B
  __shared__ __align__(16) unsigned short hsL[64 * 40];
  __shared__ float f2s[32];
  int t = threadIdx.x;
  int wv = t >> 6, lane = t & 63, quad = lane >> 4, col = lane & 15;
  int ch = blockIdx.x, it = blockIdx.y, h = blockIdx.z;
  int i0 = it * 64;
  int irow = i0 + wv * 16 + col;
  int j0c = ch * Jc;

  float f1i = f1[h * N_NODES + irow];
  float s0 = f1i + f2max[h];
  float m = fmaxf(s0, 0.2f * s0);  // lrelu monotone -> valid upper-bound shift

  float4v acc[4] = {{0,0,0,0},{0,0,0,0},{0,0,0,0},{0,0,0,0}};
  float4v accl = {0, 0, 0, 0};
  S8U ones;
  ones.u[0] = ones.u[1] = ones.u[2] = ones.u[3] = 0x3F803F80u; // bf16 1.0 x2

  const unsigned short* Hh =
      reinterpret_cast<const unsigned short*>(hThi) + (size_t)h * 64 * N_NODES;
  const unsigned short* Hl =
      reinterpret_cast<const unsigned short*>(hTlo) + (size_t)h * 64 * N_NODES;
  int sd = t >> 2, sq = t & 3;

  for (int j0 = j0c; j0 < j0c + Jc; j0 += 32) {
    __syncthreads();
    size_t goff = (size_t)sd * N_NODES + j0 + sq * 8;
    *reinterpret_cast<short8*>(&hsH[sd * 40 + sq * 8]) =
        *reinterpret_cast<const short8*>(Hh + goff);
    *reinterpret_cast<short8*>(&hsL[sd * 40 + sq * 8]) =
        *reinterpret_cast<const short8*>(Hl + goff);
    if (t < 32) f2s[t] = f2[h * N_NODES + j0 + t];
    __syncthreads();

    unsigned int word = bits32[(size_t)irow * 128 + (j0 >> 5)];
    float4v fa = *reinterpret_cast<const float4v*>(&f2s[quad * 8]);
    float4v fb = *reinterpret_cast<const float4v*>(&f2s[quad * 8 + 4]);
    float w[8];
#pragma unroll
    for (int jj = 0; jj < 8; ++jj) {
      float fv = (jj < 4) ? fa[jj & 3] : fb[jj & 3];
      float s = f1i + fv;
      float lr = fmaxf(s, 0.2f * s);            // leakyrelu, alpha=0.2
      float e = __expf(lr - m);
      w[jj] = ((word >> (quad * 8 + jj)) & 1u) ? e : 0.0f;
    }
    S8U afr;
#pragma unroll
    for (int k2 = 0; k2 < 4; ++k2) {
      union { unsigned int u; __hip_bfloat16 b[2]; } p;
      p.b[0] = __float2bfloat16(w[2 * k2]);
      p.b[1] = __float2bfloat16(w[2 * k2 + 1]);
      afr.u[k2] = p.u;
    }
#pragma unroll
    for (int db = 0; db < 4; ++db) {
      int so = (db * 16 + col) * 40 + quad * 8;
      short8 bh = *reinterpret_cast<const short8*>(&hsH[so]);
      short8 bl = *reinterpret_cast<const short8*>(&hsL[so]);
      acc[db] = __builtin_amdgcn_mfma_f32_16x16x32_bf16(afr.v, bh, acc[db], 0, 0, 0);
      acc[db] = __builtin_amdgcn_mfma_f32_16x16x32_bf16(afr.v, bl, acc[db], 0, 0, 0);
    }
    accl = __builtin_amdgcn_mfma_f32_16x16x32_bf16(afr.v, ones.v, accl, 0, 0, 0);
  }

  // C/D layout: col=lane&15, row=quad*4+reg
  float* pb = pbuf + ((size_t)(ch * 4 + h) * N_NODES + i0 + wv * 16) * 64;
#pragma unroll
  for (int db = 0; db < 4; ++db)
#pragma unroll
    for (int r = 0; r < 4; ++r)
      pb[(quad * 4 + r) * 64 + db * 16 + col] = acc[db][r];
  if (col == 0) {
    float* lb = lbuf + (size_t)(ch * 4 + h) * N_NODES + i0 + wv * 16;
#pragma unroll
    for (int r = 0; r < 4; ++r) lb[quad * 4 + r] = accl[r];
  }
}

// ------- combine chunks, normalize, elu; write fp32 OR split-bf16 --------
__global__ __launch_bounds__(256) void reduce_elu_kernel(
    const float* __restrict__ pbuf, const float* __restrict__ lbuf,
    float* __restrict__ outf, __hip_bfloat16* __restrict__ outhi,
    __hip_bfloat16* __restrict__ outlo, int NC)
{
  int idx = blockIdx.x * 256 + threadIdx.x; // n*256 + c
  int n = idx >> 8, c = idx & 255, h = c >> 6, d = c & 63;
  float s = 0.f, l = 0.f;
  for (int ch = 0; ch < NC; ++ch) {
    s += pbuf[((size_t)(ch * 4 + h) * N_NODES + n) * 64 + d];
    l += lbuf[(size_t)(ch * 4 + h) * N_NODES + n];
  }
  float v = s / l;
  float o = v > 0.f ? v : __expf(v) - 1.0f;
  if (outf) {
    outf[idx] = o;
  } else {
    __hip_bfloat16 hb = __float2bfloat16(o);
    outhi[idx] = hb;
    outlo[idx] = __float2bfloat16(o - __bfloat162float(hb));
  }
}

extern "C" void kernel_launch(void* const* d_in, const int* in_sizes, int n_in,
                              void* d_out, int out_size, void* d_ws, size_t ws_size,
                              hipStream_t stream)
{
  // inputs: t, x, adj, W1, a1, W2, a2  (all fp32 except adj int32)
  const float* x   = (const float*)d_in[1];
  const int*   adj = (const int*)d_in[2];
  const float* W1  = (const float*)d_in[3];
  const float* a1  = (const float*)d_in[4];
  const float* W2  = (const float*)d_in[5];
  const float* a2  = (const float*)d_in[6];

  char* ws = (char*)d_ws;
  size_t off = 0;
  auto alloc = [&](size_t b) { size_t o = off; off = (off + b + 255) & ~255ULL; return o; };
  size_t o_bits = alloc((size_t)N_NODES * 64 * 8);          // 2 MB bitmask
  size_t o_w1h  = alloc((size_t)DIMC * DIMC * 2);
  size_t o_w1l  = alloc((size_t)DIMC * DIMC * 2);
  size_t o_w2h  = alloc((size_t)DIMC * DIMC * 2);
  size_t o_w2l  = alloc((size_t)DIMC * DIMC * 2);
  size_t o_xh   = alloc((size_t)N_NODES * DIMC * 2);
  size_t o_xl   = alloc((size_t)N_NODES * DIMC * 2);
  size_t o_hA   = alloc((size_t)N_NODES * DIMC * 4);        // h fp32 row-major
  size_t o_hTh  = alloc((size_t)N_NODES * DIMC * 2);
  size_t o_hTl  = alloc((size_t)N_NODES * DIMC * 2);
  size_t o_x2h  = alloc((size_t)N_NODES * DIMC * 2);
  size_t o_x2l  = alloc((size_t)N_NODES * DIMC * 2);
  size_t o_f1   = alloc((size_t)NHEADS * N_NODES * 4);
  size_t o_f2   = alloc((size_t)NHEADS * N_NODES * 4);
  size_t o_fm   = alloc(256);

  size_t per_chunk = (size_t)NHEADS * N_NODES * 64 * 4 + (size_t)NHEADS * N_NODES * 4 + 512;
  int NC = 4;
  while (NC > 1 && off + (size_t)NC * per_chunk > ws_size) NC >>= 1;
  size_t o_pb = alloc((size_t)NC * NHEADS * N_NODES * 64 * 4);
  size_t o_lb = alloc((size_t)NC * NHEADS * N_NODES * 4);

  unsigned long long* bits = (unsigned long long*)(ws + o_bits);
  const unsigned int* bits32 = (const unsigned int*)(ws + o_bits);
  __hip_bfloat16* w1h = (__hip_bfloat16*)(ws + o_w1h);
  __hip_bfloat16* w1l = (__hip_bfloat16*)(ws + o_w1l);
  __hip_bfloat16* w2h = (__hip_bfloat16*)(ws + o_w2h);
  __hip_bfloat16* w2l = (__hip_bfloat16*)(ws + o_w2l);
  __hip_bfloat16* xh  = (__hip_bfloat16*)(ws + o_xh);
  __hip_bfloat16* xl  = (__hip_bfloat16*)(ws + o_xl);
  float*          hA  = (float*)(ws + o_hA);
  __hip_bfloat16* hTh = (__hip_bfloat16*)(ws + o_hTh);
  __hip_bfloat16* hTl = (__hip_bfloat16*)(ws + o_hTl);
  __hip_bfloat16* x2h = (__hip_bfloat16*)(ws + o_x2h);
  __hip_bfloat16* x2l = (__hip_bfloat16*)(ws + o_x2l);
  float* f1p = (float*)(ws + o_f1);
  float* f2p = (float*)(ws + o_f2);
  float* fmp = (float*)(ws + o_fm);
  float* pb  = (float*)(ws + o_pb);
  float* lb  = (float*)(ws + o_lb);

  pack_adj_kernel<<<N_NODES * 64 / 4, 256, 0, stream>>>(adj, bits);
  // W[h][f][d] -> WT[(h*64+d)][f], split hi/lo
  transpose_split_kernel<<<dim3(8, 2, 4), 256, 0, stream>>>(W1, w1h, w1l, 256, 64);
  transpose_split_kernel<<<dim3(8, 2, 4), 256, 0, stream>>>(W2, w2h, w2l, 256, 64);
  split_kernel<<<N_NODES * DIMC / 256, 256, 0, stream>>>(x, xh, xl, N_NODES * DIMC);

  auto layer = [&](const __hip_bfloat16* xih, const __hip_bfloat16* xil,
                   const __hip_bfloat16* wth, const __hip_bfloat16* wtl,
                   const float* av, float* outf,
                   __hip_bfloat16* oh, __hip_bfloat16* ol) {
    gemm_kernel<<<dim3(64, 4), 256, 0, stream>>>(xih, xil, wth, wtl, hA);
    transpose_split_kernel<<<dim3(128, 8, 1), 256, 0, stream>>>(hA, hTh, hTl,
                                                                N_NODES, DIMC);
    fvec_kernel<<<dim3(16, 4), 256, 0, stream>>>(hTh, hTl, av, f1p, f2p);
    fmax_kernel<<<4, 256, 0, stream>>>(f2p, fmp);
    attn_kernel<<<dim3(NC, 64, 4), 256, 0, stream>>>(hTh, hTl, f1p, f2p, fmp,
                                                     bits32, pb, lb, N_NODES / NC);
    reduce_elu_kernel<<<(N_NODES * DIMC) / 256, 256, 0, stream>>>(pb, lb, outf, oh, ol, NC);
  };

  layer(xh,  xl,  w1h, w1l, a1, nullptr,        x2h, x2l);
  layer(x2h, x2l, w2h, w2l, a2, (float*)d_out,  nullptr, nullptr);
}